// Round 11
// baseline (2598.237 us; speedup 1.0000x reference)
//
#include <hip/hip_runtime.h>
#include <hip/hip_bf16.h>

typedef __hip_bfloat16 bf16;
typedef short short8v __attribute__((ext_vector_type(8)));
typedef float float4v __attribute__((ext_vector_type(4)));

__device__ __forceinline__ float ld_f(const float* p, size_t i) { return p[i]; }
__device__ __forceinline__ float ld_f(const bf16* p, size_t i) { return __bfloat162float(p[i]); }
__device__ __forceinline__ float bfb_to_f(short u) {
    return __uint_as_float(((unsigned int)(unsigned short)u) << 16);
}
__device__ __forceinline__ short f_to_bf16bits(float v) {
    bf16 h = __float2bfloat16(v);
    short s; __builtin_memcpy(&s, &h, 2); return s;
}
__device__ __forceinline__ unsigned int bn_pair(unsigned int u, float sc, float sh) {
    float x0 = bfb_to_f((short)(u & 0xffffu));
    float x1 = bfb_to_f((short)(u >> 16));
    float y0 = fmaxf(fmaf(sc, x0, sh), 0.0f);
    float y1 = fmaxf(fmaf(sc, x1, sh), 0.0f);
    return (unsigned int)(unsigned short)f_to_bf16bits(y0) |
           ((unsigned int)(unsigned short)f_to_bf16bits(y1) << 16);
}
__device__ __forceinline__ float sigmoidf_(float x) { return 1.0f / (1.0f + expf(-x)); }

// ---------------------------------------------------------------------------
__global__ __launch_bounds__(256) void zero_kernel(float* __restrict__ p, int n) {
    int i = blockIdx.x * 256 + threadIdx.x;
    if (i < n) p[i] = 0.0f;
}

// ---------------------------------------------------------------------------
__global__ __launch_bounds__(256) void pack_gemm(const float* __restrict__ w, short* __restrict__ out,
                                                 int M, int CIN, int KW, int KWP) {
    int idx = blockIdx.x * 256 + threadIdx.x;
    int tot = M * CIN * KWP;
    if (idx >= tot) return;
    int co = idx / (CIN * KWP);
    int r = idx - co * (CIN * KWP);
    int ci = r / KWP, t = r - ci * KWP;
    float v = (t < KW) ? w[((size_t)co * CIN + ci) * KW + t] : 0.0f;
    out[idx] = f_to_bf16bits(v);
}

// ---------------------------------------------------------------------------
__global__ __launch_bounds__(256) void pack_gruw(const float* __restrict__ whh, short* __restrict__ wfrag) {
    int idx = blockIdx.x * 256 + threadIdx.x;
    if (idx >= 196608) return;
    int j = idx & 7;
    int lane = (idx >> 3) & 63;
    int f = idx >> 9;
    int wv = f / 48;
    int r = f - wv * 48;
    int mt = r >> 3, kc = r & 7;
    int m = lane & 15, quad = lane >> 4;
    int row = (wv * 6 + mt) * 16 + m;
    int col = kc * 32 + quad * 8 + j;
    wfrag[idx] = f_to_bf16bits(whh[(size_t)row * 256 + col]);
}

// ---------------------------------------------------------------------------
// consolidated pack: w3,w4,w5 (KWP=4), wih, whh-frag in ONE dispatch.
// ---------------------------------------------------------------------------
__global__ __launch_bounds__(256) void pack_all(const float* __restrict__ w3, const float* __restrict__ w4,
                                                const float* __restrict__ w5, const float* __restrict__ wih,
                                                const float* __restrict__ whh,
                                                short* __restrict__ o3, short* __restrict__ o4,
                                                short* __restrict__ o5, short* __restrict__ owih,
                                                short* __restrict__ ogru) {
    int idx = blockIdx.x * 256 + threadIdx.x;
    const int NC = 512 * 512 * 4;
    if (idx < NC) {
        int co = idx >> 11, r = idx & 2047;
        int ci = r >> 2, t = r & 3;
        o3[idx] = f_to_bf16bits(w3[((size_t)co * 512 + ci) * 4 + t]);
        return;
    }
    idx -= NC;
    if (idx < NC) {
        int co = idx >> 11, r = idx & 2047;
        int ci = r >> 2, t = r & 3;
        o4[idx] = (t < 3) ? f_to_bf16bits(w4[((size_t)co * 512 + ci) * 3 + t]) : 0;
        return;
    }
    idx -= NC;
    if (idx < NC) {
        int co = idx >> 11, r = idx & 2047;
        int ci = r >> 2, t = r & 3;
        o5[idx] = (t < 3) ? f_to_bf16bits(w5[((size_t)co * 512 + ci) * 3 + t]) : 0;
        return;
    }
    idx -= NC;
    if (idx < 393216) {
        owih[idx] = f_to_bf16bits(wih[idx]);
        return;
    }
    idx -= 393216;
    if (idx < 196608) {
        int j = idx & 7;
        int lane = (idx >> 3) & 63;
        int f = idx >> 9;
        int wv = f / 48;
        int r = f - wv * 48;
        int mt = r >> 3, kc = r & 7;
        int m = lane & 15, quad = lane >> 4;
        int row = (wv * 6 + mt) * 16 + m;
        int col = kc * 32 + quad * 8 + j;
        ogru[idx] = f_to_bf16bits(whh[(size_t)row * 256 + col]);
    }
}

// ---------------------------------------------------------------------------
__global__ __launch_bounds__(256) void bn_fin(const float* __restrict__ sums, const float* __restrict__ gamma,
                                              const float* __restrict__ beta, int layer, float invM,
                                              float* __restrict__ ss) {
    int c = blockIdx.x * 256 + threadIdx.x;
    if (c >= 512) return;
    float mean = sums[c] * invM;
    float var = sums[512 + c] * invM - mean * mean;
    float sc = rsqrtf(var + 1e-5f) * gamma[layer * 512 + c];
    ss[c] = sc;
    ss[512 + c] = beta[layer * 512 + c] - mean * sc;
}

// ---------------------------------------------------------------------------
// conv v6 (layer 2): 128co x 128l tile, 1x4 waves, dbuf LDS, vectorized
// staging, optional fused input-BN and output stats.
// ---------------------------------------------------------------------------
template <int KWP, int ST, int SPANP, bool BNIN, bool STATS>
__global__ __launch_bounds__(256, 3) void conv_mfma6(const bf16* __restrict__ in,
                                                     const short* __restrict__ wpk,
                                                     bf16* __restrict__ out,
                                                     int Lin, int Lout, int pad,
                                                     const float* __restrict__ ssin,
                                                     float* __restrict__ sums_out) {
    constexpr int KTOT = 512 * KWP;
    constexpr int NCHUNK = KTOT / 32;
    constexpr int CCC = 32 / KWP;
    constexpr int W16 = SPANP / 8;
    constexpr int NU = CCC * W16;
    constexpr int NLD = (NU + 255) / 256;

    const int l0 = blockIdx.x * 128;
    const int co0 = blockIdx.y * 128;
    const int tid = threadIdx.x;
    const int lane = tid & 63;
    const int wv = tid >> 6;
    const int m = lane & 15;
    const int quad = lane >> 4;
    const int nh = wv * 32;

    in += (size_t)blockIdx.z * 512 * Lin;
    out += (size_t)blockIdx.z * 512 * Lout;
    const short* ins = (const short*)in;

    __shared__ __align__(16) short As[2][128][40];
    __shared__ __align__(16) short rows[2][CCC][SPANP];
    __shared__ float bsum[STATS ? 128 : 1][2];

    const int base = ST * l0 - pad;
    const int g0a = base & ~7;
    const int off = base - g0a;

    const int arow = tid >> 2, aseg = tid & 3;

    float4v acc[8][2];
#pragma unroll
    for (int i = 0; i < 8; ++i) { acc[i][0] = (float4v){0,0,0,0}; acc[i][1] = (float4v){0,0,0,0}; }

    uint4 pa0, pa1;
    uint4 rbuf[NLD];

    auto load_stage = [&](int kc) {
        const int k0 = kc * 32;
        const int ci0 = kc * CCC;
        pa0 = *(const uint4*)(wpk + (size_t)(co0 + arow) * KTOT + k0 + aseg * 8);
        pa1 = *(const uint4*)(wpk + (size_t)(co0 + arow + 64) * KTOT + k0 + aseg * 8);
#pragma unroll
        for (int r = 0; r < NLD; ++r) {
            int e = tid + r * 256;
            if (NU % 256 == 0 || e < NU) {
                int cc = e / W16, col = e - cc * W16;
                int gs = g0a + col * 8;
                const short* src = ins + (size_t)(ci0 + cc) * Lin;
                if (gs >= 0 && gs + 8 <= Lin) {
                    rbuf[r] = *(const uint4*)(src + gs);
                } else {
                    float sc = 0.f, sh = 0.f;
                    if constexpr (BNIN) { sc = ssin[ci0 + cc]; sh = ssin[512 + ci0 + cc]; }
                    unsigned short tmp[8];
#pragma unroll
                    for (int j = 0; j < 8; ++j) {
                        int g = gs + j;
                        float xv = 0.f;
                        if (g >= 0 && g < Lin) {
                            xv = bfb_to_f(src[g]);
                            if constexpr (BNIN) xv = fmaxf(fmaf(sc, xv, sh), 0.0f);
                        }
                        tmp[j] = (unsigned short)f_to_bf16bits(xv);
                    }
                    uint4 v;
                    v.x = tmp[0] | ((unsigned int)tmp[1] << 16);
                    v.y = tmp[2] | ((unsigned int)tmp[3] << 16);
                    v.z = tmp[4] | ((unsigned int)tmp[5] << 16);
                    v.w = tmp[6] | ((unsigned int)tmp[7] << 16);
                    rbuf[r] = v;
                }
            }
        }
    };
    auto commit = [&](int buf, int kc) {
        *(uint4*)&As[buf][arow][aseg * 8] = pa0;
        *(uint4*)&As[buf][arow + 64][aseg * 8] = pa1;
        const int ci0 = kc * CCC;
#pragma unroll
        for (int r = 0; r < NLD; ++r) {
            int e = tid + r * 256;
            if (NU % 256 == 0 || e < NU) {
                int cc = e / W16, col = e - cc * W16;
                uint4 v = rbuf[r];
                if constexpr (BNIN) {
                    int gs = g0a + col * 8;
                    if (gs >= 0 && gs + 8 <= Lin) {
                        float sc = ssin[ci0 + cc], sh = ssin[512 + ci0 + cc];
                        v.x = bn_pair(v.x, sc, sh);
                        v.y = bn_pair(v.y, sc, sh);
                        v.z = bn_pair(v.z, sc, sh);
                        v.w = bn_pair(v.w, sc, sh);
                    }
                }
                *(uint4*)&rows[buf][cc][col * 8] = v;
            }
        }
    };

    if (STATS && tid < 128) { bsum[tid][0] = 0.f; bsum[tid][1] = 0.f; }
    load_stage(0);
    commit(0, 0);
    __syncthreads();

    for (int kc = 0; kc < NCHUNK; ++kc) {
        const int cur = kc & 1;
        if (kc + 1 < NCHUNK) load_stage(kc + 1);

        short8v afrag[8], bfrag[2];
#pragma unroll
        for (int s = 0; s < 8; ++s)
            afrag[s] = *(const short8v*)&As[cur][s * 16 + m][quad * 8];
#pragma unroll
        for (int t = 0; t < 2; ++t) {
            const int ll = nh + t * 16 + m;
            short8v bf;
            if constexpr (KWP == 8) {
                const short* rp = &rows[cur][quad][off + ST * ll];
#pragma unroll
                for (int j = 0; j < 8; ++j) bf[j] = rp[j];
            } else {
                const short* ra = &rows[cur][quad * 2 + 0][off + ST * ll];
                const short* rb = &rows[cur][quad * 2 + 1][off + ST * ll];
#pragma unroll
                for (int j = 0; j < 4; ++j) { bf[j] = ra[j]; bf[4 + j] = rb[j]; }
            }
            bfrag[t] = bf;
        }
#pragma unroll
        for (int s = 0; s < 8; ++s)
#pragma unroll
            for (int t = 0; t < 2; ++t)
                acc[s][t] = __builtin_amdgcn_mfma_f32_16x16x32_bf16(afrag[s], bfrag[t], acc[s][t], 0, 0, 0);

        if (kc + 1 < NCHUNK) commit(cur ^ 1, kc + 1);
        __syncthreads();
    }

    const bool v0 = (l0 + nh + m) < Lout;
    const bool v1 = (l0 + nh + 16 + m) < Lout;
#pragma unroll
    for (int t = 0; t < 2; ++t) {
        const int l = l0 + nh + t * 16 + m;
        if (t ? v1 : v0) {
#pragma unroll
            for (int s = 0; s < 8; ++s) {
#pragma unroll
                for (int reg = 0; reg < 4; ++reg) {
                    const int co = co0 + s * 16 + quad * 4 + reg;
                    out[(size_t)co * Lout + l] = __float2bfloat16(acc[s][t][reg]);
                }
            }
        }
    }

    if constexpr (STATS) {
#pragma unroll
        for (int s = 0; s < 8; ++s) {
            float p1[4], p2[4];
#pragma unroll
            for (int reg = 0; reg < 4; ++reg) {
                float a0 = v0 ? acc[s][0][reg] : 0.f;
                float a1 = v1 ? acc[s][1][reg] : 0.f;
                p1[reg] = a0 + a1;
                p2[reg] = a0 * a0 + a1 * a1;
            }
#pragma unroll
            for (int o = 1; o <= 8; o <<= 1) {
#pragma unroll
                for (int reg = 0; reg < 4; ++reg) {
                    p1[reg] += __shfl_xor(p1[reg], o);
                    p2[reg] += __shfl_xor(p2[reg], o);
                }
            }
            if (m == 0) {
#pragma unroll
                for (int reg = 0; reg < 4; ++reg) {
                    atomicAdd(&bsum[s * 16 + quad * 4 + reg][0], p1[reg]);
                    atomicAdd(&bsum[s * 16 + quad * 4 + reg][1], p2[reg]);
                }
            }
        }
        __syncthreads();
        if (tid < 128) {
            atomicAdd(&sums_out[co0 + tid], bsum[tid][0]);
            atomicAdd(&sums_out[512 + co0 + tid], bsum[tid][1]);
        }
    }
}

// ---------------------------------------------------------------------------
// conv v8 (layers 3-5): 256co x 64l tile, 2x2 waves (wave = 128co x 32l,
// acc[8][2] -- v6's proven register envelope, NO spill). Input staged twice
// fewer times than v6 (co re-read 4 -> 2). LDS ~47 KB -> 3 blocks/CU.
// ---------------------------------------------------------------------------
template <int KWP, int ST, int SPANP, bool BNIN, bool STATS>
__global__ __launch_bounds__(256, 3) void conv_mfma8(const bf16* __restrict__ in,
                                                     const short* __restrict__ wpk,
                                                     bf16* __restrict__ out,
                                                     int Lin, int Lout, int pad,
                                                     const float* __restrict__ ssin,
                                                     float* __restrict__ sums_out) {
    constexpr int KTOT = 512 * KWP;
    constexpr int NCHUNK = KTOT / 32;
    constexpr int CCC = 32 / KWP;
    constexpr int W16 = SPANP / 8;
    constexpr int NU = CCC * W16;        // <= 256 for SPANP in {144, 80}

    const int l0 = blockIdx.x * 64;
    const int co0 = blockIdx.y * 256;
    const int tid = threadIdx.x;
    const int lane = tid & 63;
    const int wv = tid >> 6;
    const int m = lane & 15;
    const int quad = lane >> 4;
    const int ch = (wv >> 1) * 128;      // wave co offset within 256-tile
    const int wl = (wv & 1) * 32;        // wave l offset within 64-tile

    in += (size_t)blockIdx.z * 512 * Lin;
    out += (size_t)blockIdx.z * 512 * Lout;
    const short* ins = (const short*)in;

    __shared__ __align__(16) short As[2][256][40];
    __shared__ __align__(16) short rows[2][CCC][SPANP];
    __shared__ float bsum[STATS ? 256 : 1][2];

    const int base = ST * l0 - pad;
    const int g0a = base & ~7;
    const int off = base - g0a;

    const int arow = tid >> 2, aseg = tid & 3;   // A: 4 x uint4/thread (rows +0,+64,+128,+192)

    float4v acc[8][2];
#pragma unroll
    for (int i = 0; i < 8; ++i) { acc[i][0] = (float4v){0,0,0,0}; acc[i][1] = (float4v){0,0,0,0}; }

    uint4 pa[4];
    uint4 rb;

    auto load_stage = [&](int kc) {
        const int k0 = kc * 32;
        const int ci0 = kc * CCC;
#pragma unroll
        for (int r = 0; r < 4; ++r)
            pa[r] = *(const uint4*)(wpk + (size_t)(co0 + arow + r * 64) * KTOT + k0 + aseg * 8);
        if (tid < NU) {
            int cc = tid / W16, col = tid - cc * W16;
            int gs = g0a + col * 8;
            const short* src = ins + (size_t)(ci0 + cc) * Lin;
            if (gs >= 0 && gs + 8 <= Lin) {
                rb = *(const uint4*)(src + gs);
            } else {
                float sc = 0.f, sh = 0.f;
                if constexpr (BNIN) { sc = ssin[ci0 + cc]; sh = ssin[512 + ci0 + cc]; }
                unsigned short tmp[8];
#pragma unroll
                for (int j = 0; j < 8; ++j) {
                    int g = gs + j;
                    float xv = 0.f;
                    if (g >= 0 && g < Lin) {
                        xv = bfb_to_f(src[g]);
                        if constexpr (BNIN) xv = fmaxf(fmaf(sc, xv, sh), 0.0f);
                    }
                    tmp[j] = (unsigned short)f_to_bf16bits(xv);
                }
                uint4 v;
                v.x = tmp[0] | ((unsigned int)tmp[1] << 16);
                v.y = tmp[2] | ((unsigned int)tmp[3] << 16);
                v.z = tmp[4] | ((unsigned int)tmp[5] << 16);
                v.w = tmp[6] | ((unsigned int)tmp[7] << 16);
                rb = v;
            }
        }
    };
    auto commit = [&](int buf, int kc) {
#pragma unroll
        for (int r = 0; r < 4; ++r)
            *(uint4*)&As[buf][arow + r * 64][aseg * 8] = pa[r];
        if (tid < NU) {
            int cc = tid / W16, col = tid - cc * W16;
            uint4 v = rb;
            if constexpr (BNIN) {
                int gs = g0a + col * 8;
                if (gs >= 0 && gs + 8 <= Lin) {
                    const int ci0 = kc * CCC;
                    float sc = ssin[ci0 + cc], sh = ssin[512 + ci0 + cc];
                    v.x = bn_pair(v.x, sc, sh);
                    v.y = bn_pair(v.y, sc, sh);
                    v.z = bn_pair(v.z, sc, sh);
                    v.w = bn_pair(v.w, sc, sh);
                }
            }
            *(uint4*)&rows[buf][cc][col * 8] = v;
        }
    };

    if (STATS) { bsum[tid][0] = 0.f; bsum[tid][1] = 0.f; }
    load_stage(0);
    commit(0, 0);
    __syncthreads();

    for (int kc = 0; kc < NCHUNK; ++kc) {
        const int cur = kc & 1;
        if (kc + 1 < NCHUNK) load_stage(kc + 1);

        short8v afrag[8], bfrag[2];
#pragma unroll
        for (int s = 0; s < 8; ++s)
            afrag[s] = *(const short8v*)&As[cur][ch + s * 16 + m][quad * 8];
#pragma unroll
        for (int t = 0; t < 2; ++t) {
            const int ll = wl + t * 16 + m;
            short8v bf;
            if constexpr (KWP == 8) {
                const short* rp = &rows[cur][quad][off + ST * ll];
#pragma unroll
                for (int j = 0; j < 8; ++j) bf[j] = rp[j];
            } else {
                const short* ra = &rows[cur][quad * 2 + 0][off + ST * ll];
                const short* rb2 = &rows[cur][quad * 2 + 1][off + ST * ll];
#pragma unroll
                for (int j = 0; j < 4; ++j) { bf[j] = ra[j]; bf[4 + j] = rb2[j]; }
            }
            bfrag[t] = bf;
        }
#pragma unroll
        for (int s = 0; s < 8; ++s)
#pragma unroll
            for (int t = 0; t < 2; ++t)
                acc[s][t] = __builtin_amdgcn_mfma_f32_16x16x32_bf16(afrag[s], bfrag[t], acc[s][t], 0, 0, 0);

        if (kc + 1 < NCHUNK) commit(cur ^ 1, kc + 1);
        __syncthreads();
    }

    const bool v0 = (l0 + wl + m) < Lout;
    const bool v1 = (l0 + wl + 16 + m) < Lout;
#pragma unroll
    for (int t = 0; t < 2; ++t) {
        const int l = l0 + wl + t * 16 + m;
        if (t ? v1 : v0) {
#pragma unroll
            for (int s = 0; s < 8; ++s) {
#pragma unroll
                for (int reg = 0; reg < 4; ++reg) {
                    const int co = co0 + ch + s * 16 + quad * 4 + reg;
                    out[(size_t)co * Lout + l] = __float2bfloat16(acc[s][t][reg]);
                }
            }
        }
    }

    if constexpr (STATS) {
#pragma unroll
        for (int s = 0; s < 8; ++s) {
            float p1[4], p2[4];
#pragma unroll
            for (int reg = 0; reg < 4; ++reg) {
                float a0 = v0 ? acc[s][0][reg] : 0.f;
                float a1 = v1 ? acc[s][1][reg] : 0.f;
                p1[reg] = a0 + a1;
                p2[reg] = a0 * a0 + a1 * a1;
            }
#pragma unroll
            for (int o = 1; o <= 8; o <<= 1) {
#pragma unroll
                for (int reg = 0; reg < 4; ++reg) {
                    p1[reg] += __shfl_xor(p1[reg], o);
                    p2[reg] += __shfl_xor(p2[reg], o);
                }
            }
            if (m == 0) {
#pragma unroll
                for (int reg = 0; reg < 4; ++reg) {
                    atomicAdd(&bsum[ch + s * 16 + quad * 4 + reg][0], p1[reg]);
                    atomicAdd(&bsum[ch + s * 16 + quad * 4 + reg][1], p2[reg]);
                }
            }
        }
        __syncthreads();
        atomicAdd(&sums_out[co0 + tid], bsum[tid][0]);
        atomicAdd(&sums_out[512 + co0 + tid], bsum[tid][1]);
    }
}

// ---------------------------------------------------------------------------
__global__ __launch_bounds__(256) void conv1_mfma(const float* __restrict__ x,
                                                  const short* __restrict__ w1p,
                                                  const float* __restrict__ ss,
                                                  bf16* __restrict__ y1c, int nbase) {
    const int l0 = blockIdx.x * 64;
    const int co0 = blockIdx.y * 128;
    const int nloc = blockIdx.z;
    const int n = nbase + nloc;
    const int tid = threadIdx.x;
    const int lane = tid & 63;
    const int wv = tid >> 6;
    const int m = lane & 15;
    const int quad = lane >> 4;

    __shared__ __align__(16) short xs[352];
    const int base = 5 * l0 - 3;
    for (int e = tid; e < 347; e += 256) {
        int g = base + e;
        float v = (g >= 0 && g < 20480) ? x[(size_t)n * 20480 + g] : 0.0f;
        xs[e] = f_to_bf16bits(v);
    }
    __syncthreads();

    const int lloc = wv * 16 + m;
    short8v bfrag;
    {
        const short* rp = &xs[5 * lloc + quad * 8];
#pragma unroll
        for (int j = 0; j < 8; ++j) bfrag[j] = rp[j];
    }
    float4v acc[8];
#pragma unroll
    for (int s = 0; s < 8; ++s) {
        short8v afrag = *(const short8v*)(w1p + (size_t)(co0 + s * 16 + m) * 32 + quad * 8);
        float4v z = (float4v){0.f, 0.f, 0.f, 0.f};
        acc[s] = __builtin_amdgcn_mfma_f32_16x16x32_bf16(afrag, bfrag, z, 0, 0, 0);
    }
    const int l = l0 + lloc;
#pragma unroll
    for (int s = 0; s < 8; ++s) {
#pragma unroll
        for (int reg = 0; reg < 4; ++reg) {
            const int co = co0 + s * 16 + quad * 4 + reg;
            float v = fmaxf(acc[s][reg] * ss[co] + ss[512 + co], 0.0f);
            y1c[((size_t)nloc * 512 + co) * 4096 + l] = __float2bfloat16(v);
        }
    }
}

// ---------------------------------------------------------------------------
__global__ __launch_bounds__(256) void conv1_stats(const float* __restrict__ x,
                                                   const float* __restrict__ w1,
                                                   float* __restrict__ sums) {
    const int n = blockIdx.x;
    const int tid = threadIdx.x;
    __shared__ __align__(16) float ws[5120];
    __shared__ __align__(16) float xs[5 * 256 + 10];
    for (int e = tid; e < 5120; e += 256) ws[e] = w1[e];
    const int co0 = tid, co1 = tid + 256;
    float a1_0 = 0.0f, a2_0 = 0.0f, a1_1 = 0.0f, a2_1 = 0.0f;
    for (int i = 0; i < 4; ++i) {
        const int c = blockIdx.y * 4 + i;
        const int base = c * 1280 - 3;
        __syncthreads();
        for (int e = tid; e < 1290; e += 256) {
            int g = base + e;
            xs[e] = (g >= 0 && g < 20480) ? x[(size_t)n * 20480 + g] : 0.0f;
        }
        __syncthreads();
        for (int l = 0; l < 256; ++l) {
            float y0 = 0.0f, y1v = 0.0f;
#pragma unroll
            for (int t = 0; t < 10; ++t) {
                float xv = xs[5 * l + t];
                y0 += ws[co0 * 10 + t] * xv;
                y1v += ws[co1 * 10 + t] * xv;
            }
            a1_0 += y0; a2_0 += y0 * y0;
            a1_1 += y1v; a2_1 += y1v * y1v;
        }
    }
    atomicAdd(&sums[co0], a1_0); atomicAdd(&sums[512 + co0], a2_0);
    atomicAdd(&sums[co1], a1_1); atomicAdd(&sums[512 + co1], a2_1);
}

// ---------------------------------------------------------------------------
__global__ __launch_bounds__(256) void bn_stats_v(const bf16* __restrict__ y, float* __restrict__ sums, int L) {
    const int c = blockIdx.x, n = blockIdx.y;
    const short* p = (const short*)y + ((size_t)n * 512 + c) * L;
    float s1 = 0.f, s2 = 0.f;
    for (int l = threadIdx.x; l < L; l += 256) {
        float v = bfb_to_f(p[l]);
        s1 += v; s2 += v * v;
    }
#pragma unroll
    for (int off = 32; off > 0; off >>= 1) {
        s1 += __shfl_down(s1, off, 64);
        s2 += __shfl_down(s2, off, 64);
    }
    __shared__ float r1[4], r2[4];
    const int lane = threadIdx.x & 63, wv = threadIdx.x >> 6;
    if (lane == 0) { r1[wv] = s1; r2[wv] = s2; }
    __syncthreads();
    if (threadIdx.x == 0) {
        atomicAdd(&sums[c], r1[0] + r1[1] + r1[2] + r1[3]);
        atomicAdd(&sums[512 + c], r2[0] + r2[1] + r2[2] + r2[3]);
    }
}

// ---------------------------------------------------------------------------
__global__ __launch_bounds__(256) void bn_apply_v(bf16* __restrict__ y, const float* __restrict__ sums,
                                                  const float* __restrict__ gamma, const float* __restrict__ beta,
                                                  int layer, int L) {
    const int c = blockIdx.x, n = blockIdx.y;
    const float invM = 1.0f / (64.0f * (float)L);
    float mean = sums[c] * invM;
    float var = sums[512 + c] * invM - mean * mean;
    float sc = rsqrtf(var + 1e-5f) * gamma[layer * 512 + c];
    float sh = beta[layer * 512 + c] - mean * sc;
    short* p = (short*)y + ((size_t)n * 512 + c) * L;
    for (int l = threadIdx.x; l < L; l += 256) {
        float v = bfb_to_f(p[l]);
        p[l] = f_to_bf16bits(fmaxf(v * sc + sh, 0.0f));
    }
}

// ---------------------------------------------------------------------------
// xproj with y5-BN folded into staging.
// ---------------------------------------------------------------------------
__global__ __launch_bounds__(256) void xproj_mfma(const bf16* __restrict__ y5,
                                                  const short* __restrict__ wihp,
                                                  const float* __restrict__ bih,
                                                  const float* __restrict__ ssy,
                                                  float* __restrict__ xp,
                                                  const int* __restrict__ tsamp) {
    const int t0 = blockIdx.x * 64;
    const int g0 = blockIdx.y * 128;
    const int b = blockIdx.z;
    const int tid = threadIdx.x;
    const int lane = tid & 63;
    const int wv = tid >> 6;
    const int m = lane & 15;
    const int quad = lane >> 4;
    const int ts = tsamp[0];

    __shared__ __align__(16) short As[128][40];
    __shared__ __align__(16) short Bt[32][66];

    float4v acc[8];
#pragma unroll
    for (int i = 0; i < 8; ++i) acc[i] = (float4v){0.f, 0.f, 0.f, 0.f};

    const short* y5s = (const short*)y5;
    for (int kc = 0; kc < 16; ++kc) {
        const int k0 = kc * 32;
        __syncthreads();
#pragma unroll
        for (int r = 0; r < 2; ++r) {
            int e = tid + r * 256;
            int row = e >> 2, seg = e & 3;
            *(uint4*)&As[row][seg * 8] =
                *(const uint4*)(wihp + (size_t)(g0 + row) * 512 + k0 + seg * 8);
        }
        for (int e = tid; e < 2048; e += 256) {
            int cc = e >> 6, tl = e & 63;
            float sc = ssy[k0 + cc], sh = ssy[512 + k0 + cc];
            float xv = bfb_to_f(y5s[((size_t)b * 512 + k0 + cc) * 409 + t0 + tl]);
            Bt[cc][tl] = f_to_bf16bits(fmaxf(fmaf(sc, xv, sh), 0.0f));
        }
        __syncthreads();
        short8v bfrag;
#pragma unroll
        for (int j = 0; j < 8; ++j) bfrag[j] = Bt[quad * 8 + j][wv * 16 + m];
#pragma unroll
        for (int s = 0; s < 8; ++s) {
            short8v afrag = *(const short8v*)&As[s * 16 + m][quad * 8];
            acc[s] = __builtin_amdgcn_mfma_f32_16x16x32_bf16(afrag, bfrag, acc[s], 0, 0, 0);
        }
    }
    const int t = t0 + wv * 16 + m;
    if (t <= ts) {
#pragma unroll
        for (int s = 0; s < 8; ++s) {
#pragma unroll
            for (int reg = 0; reg < 4; ++reg) {
                const int g = g0 + s * 16 + quad * 4 + reg;
                xp[((size_t)b * 256 + t) * 768 + g] = acc[s][reg] + bih[g];
            }
        }
    }
}

// ---------------------------------------------------------------------------
__global__ __launch_bounds__(512, 2) void gru_mfma(const float* __restrict__ xproj,
                                                   const short* __restrict__ wfrag,
                                                   const float* __restrict__ hidden,
                                                   const float* __restrict__ bhh,
                                                   float* __restrict__ hlast,
                                                   const int* __restrict__ tsamp) {
    const int b = blockIdx.x;
    const int tid = threadIdx.x;
    const int lane = tid & 63;
    const int wv = tid >> 6;
    const int m = lane & 15;
    const int quad = lane >> 4;

    __shared__ float hf[256];
    __shared__ __align__(16) short hbs[256];
    __shared__ float pre[768];

    short8v wreg[48];
    {
        const short* wb = wfrag + ((size_t)(wv * 48) * 64 + lane) * 8;
#pragma unroll
        for (int f = 0; f < 48; ++f) wreg[f] = *(const short8v*)(wb + (size_t)f * 512);
    }
    if (wv < 4) {
        float hv = hidden[(size_t)b * 256 + tid];
        hf[tid] = hv;
        hbs[tid] = f_to_bf16bits(hv);
    }
    const int ts = tsamp[0];
    const float* xb = xproj + (size_t)b * 256 * 768;
    float bhr = 0.f, bhz = 0.f, bhn = 0.f, nxr = 0.f, nxz = 0.f, nxn = 0.f;
    if (wv < 4) {
        bhr = bhh[tid]; bhz = bhh[256 + tid]; bhn = bhh[512 + tid];
        nxr = xb[tid]; nxz = xb[256 + tid]; nxn = xb[512 + tid];
    }

    for (int step = 0; step <= ts; ++step) {
        __syncthreads();
        float4v acc[6];
#pragma unroll
        for (int i = 0; i < 6; ++i) acc[i] = (float4v){0.f, 0.f, 0.f, 0.f};
#pragma unroll
        for (int kc = 0; kc < 8; ++kc) {
            short8v bfrag = *(const short8v*)&hbs[kc * 32 + quad * 8];
#pragma unroll
            for (int mt = 0; mt < 6; ++mt)
                acc[mt] = __builtin_amdgcn_mfma_f32_16x16x32_bf16(wreg[mt * 8 + kc], bfrag, acc[mt], 0, 0, 0);
        }
        if (m == 0) {
#pragma unroll
            for (int mt = 0; mt < 6; ++mt)
#pragma unroll
                for (int reg = 0; reg < 4; ++reg)
                    pre[wv * 96 + mt * 16 + quad * 4 + reg] = acc[mt][reg];
        }
        __syncthreads();
        if (wv < 4) {
            const int g = tid;
            float r = sigmoidf_(nxr + bhr + pre[g]);
            float z = sigmoidf_(nxz + bhz + pre[256 + g]);
            float nn = tanhf(nxn + r * (bhn + pre[512 + g]));
            float hnew = (1.0f - z) * nn + z * hf[g];
            hf[g] = hnew;
            hbs[g] = f_to_bf16bits(hnew);
            if (step < ts) {
                const float* xs = xb + (size_t)(step + 1) * 768;
                nxr = xs[g]; nxz = xs[256 + g]; nxn = xs[512 + g];
            }
        }
    }
    __syncthreads();
    if (wv < 4) hlast[(size_t)b * 256 + tid] = hf[tid];
}

// ---------------------------------------------------------------------------
__global__ __launch_bounds__(256) void pred_kernel(const float* __restrict__ hlast, const float* __restrict__ wkw,
                                                   const float* __restrict__ wkb, float* __restrict__ pred) {
    const int c = blockIdx.x, t = blockIdx.y;
    __shared__ __align__(16) float hs[256];
    hs[threadIdx.x] = hlast[(size_t)c * 256 + threadIdx.x];
    __syncthreads();
    for (int k = threadIdx.x; k < 512; k += 256) {
        const float* wr = wkw + ((size_t)t * 512 + k) * 256;
        float acc = 0.0f;
        for (int d = 0; d < 256; d += 4) {
            float4 w4 = *(const float4*)&wr[d];
            acc += w4.x * hs[d] + w4.y * hs[d + 1] + w4.z * hs[d + 2] + w4.w * hs[d + 3];
        }
        pred[((size_t)t * 64 + c) * 512 + k] = acc + wkb[(size_t)t * 512 + k];
    }
}

// ---------------------------------------------------------------------------
__global__ __launch_bounds__(64) void total_kernel(const bf16* __restrict__ y5, const float* __restrict__ pred,
                                                   const float* __restrict__ ssy,
                                                   float* __restrict__ total, const int* __restrict__ tsamp) {
    const int b = blockIdx.x, t = blockIdx.y;
    const int col = tsamp[0] + 1 + t;
    __shared__ __align__(16) float es[512];
    for (int k = threadIdx.x; k < 512; k += 64) {
        float xv = ld_f(y5, ((size_t)b * 512 + k) * 409 + col);
        es[k] = fmaxf(fmaf(ssy[k], xv, ssy[512 + k]), 0.0f);
    }
    __syncthreads();
    const int c = threadIdx.x;
    const float* pr = pred + ((size_t)t * 64 + c) * 512;
    float acc = 0.0f;
    for (int k = 0; k < 512; k += 4) {
        float4 p4 = *(const float4*)&pr[k];
        acc += p4.x * es[k] + p4.y * es[k + 1] + p4.z * es[k + 2] + p4.w * es[k + 3];
    }
    total[((size_t)t * 64 + b) * 64 + c] = acc;
}

// ---------------------------------------------------------------------------
__global__ __launch_bounds__(256) void final_kernel(const float* __restrict__ total, const float* __restrict__ hlast,
                                                    float* __restrict__ out) {
    __shared__ float rowM[768], rowS[768];
    __shared__ float red[256];
    __shared__ int cnt[64];
    const int tid = threadIdx.x;
    float local = 0.0f;
    for (int row = tid; row < 768; row += 256) {
        const float* r = total + (size_t)row * 64;
        float m = r[0];
        for (int c = 1; c < 64; ++c) m = fmaxf(m, r[c]);
        float s = 0.0f;
        for (int c = 0; c < 64; ++c) s += expf(r[c] - m);
        rowM[row] = m; rowS[row] = s;
        int bcol = row & 63;
        local += r[bcol] - m - logf(s);
    }
    red[tid] = local;
    __syncthreads();
    for (int o = 128; o > 0; o >>= 1) {
        if (tid < o) red[tid] += red[tid + o];
        __syncthreads();
    }
    if (tid == 0) out[1] = red[0] / (-768.0f);
    if (tid < 64) {
        const int c = tid;
        float best = -1e30f; int bi = -1;
        for (int b = 0; b < 64; ++b) {
            int row = 11 * 64 + b;
            float v = expf(total[(size_t)row * 64 + c] - rowM[row]) / rowS[row];
            if (v > best) { best = v; bi = b; }
        }
        cnt[c] = (bi == c) ? 1 : 0;
    }
    __syncthreads();
    if (tid == 0) {
        int s = 0;
        for (int c = 0; c < 64; ++c) s += cnt[c];
        out[0] = (float)s / 64.0f;
    }
    for (int i = tid; i < 16384; i += 256) out[2 + i] = hlast[i];
}

// ---------------------------------------------------------------------------
extern "C" void kernel_launch(void* const* d_in, const int* in_sizes, int n_in,
                              void* d_out, int out_size, void* d_ws, size_t ws_size,
                              hipStream_t stream) {
    const float *x = nullptr, *hidden = nullptr, *gamma = nullptr, *beta = nullptr;
    const float *wih = nullptr, *whh = nullptr, *bih = nullptr, *bhh = nullptr;
    const float *wkw = nullptr, *wkb = nullptr;
    const float *w1 = nullptr, *w2 = nullptr, *w3 = nullptr, *w4 = nullptr, *w5 = nullptr;
    const int* tsamp = nullptr;
    for (int i = 0; i < n_in; ++i) {
        const float* p = (const float*)d_in[i];
        switch (in_sizes[i]) {
            case 1310720: x = p; break;
            case 16384:   hidden = p; break;
            case 2560:    if (!gamma) gamma = p; else beta = p; break;
            case 393216:  wih = p; break;
            case 196608:  whh = p; break;
            case 768:     if (!bih) bih = p; else bhh = p; break;
            case 1572864: wkw = p; break;
            case 6144:    wkb = p; break;
            case 1:       tsamp = (const int*)d_in[i]; break;
            case 5120:    w1 = p; break;
            case 2097152: w2 = p; break;
            case 1048576: w3 = p; break;
            case 786432:  if (!w4) w4 = p; else w5 = p; break;
            default: break;
        }
    }

    char* ws = (char*)d_ws;
    const size_t SLOT_B = 57872384ull;
    int NBC = 8;
    if (ws_size >= SLOT_B + 64ull * 4194304ull + 98304ull) NBC = 64;
    else if (ws_size >= SLOT_B + 32ull * 4194304ull + 98304ull) NBC = 32;
    else if (ws_size >= SLOT_B + 16ull * 4194304ull + 98304ull) NBC = 16;

    bf16*  y2    = (bf16*)(ws + 0);
    bf16*  y4    = (bf16*)(ws + 0);
    float* xp    = (float*)(ws + 0);
    short* wconv = (short*)(ws + 53676032ull);
    bf16*  y1c   = (bf16*)(ws + SLOT_B);
    bf16*  y3    = (bf16*)(ws + SLOT_B);
    bf16*  y5    = (bf16*)(ws + SLOT_B);
    const size_t tail = SLOT_B + (size_t)NBC * 4194304ull;
    float* sums  = (float*)(ws + tail);
    float* ss1   = (float*)(ws + tail + 20480ull);
    float* ss2   = (float*)(ws + tail + 24576ull);
    float* ss3   = (float*)(ws + tail + 28672ull);
    float* ss4   = (float*)(ws + tail + 32768ull);
    float* ss5   = (float*)(ws + tail + 36864ull);
    short* w1p   = (short*)(ws + tail + 40960ull);

    float* hlast = (float*)(ws + 54855680ull);
    float* pred  = (float*)(ws + 54921216ull);
    float* totl  = (float*)(ws + 56494080ull);

    short *wpk3, *wpk4, *wpk5, *wihp, *wfrag;
    if (NBC == 64) {
        wpk3  = (short*)(ws + SLOT_B + 33554432ull);
        wpk4  = wpk3 + 1048576;
        wpk5  = wpk4 + 1048576;
        wihp  = wpk5 + 1048576;
        wfrag = wihp + 393216;
    } else {
        wpk3 = wpk4 = wpk5 = wconv;
        wihp  = (short*)(ws + 53676032ull);
        wfrag = (short*)(ws + 54462464ull);
    }

    // --- layer-1 stats + packs ---
    zero_kernel<<<20, 256, 0, stream>>>(sums, 5120);
    conv1_stats<<<dim3(64, 4), 256, 0, stream>>>(x, w1, sums);
    bn_fin<<<2, 256, 0, stream>>>(sums, gamma, beta, 0, 1.0f / (64.0f * 4096.0f), ss1);
    pack_gemm<<<64, 256, 0, stream>>>(w1, w1p, 512, 1, 10, 32);
    pack_gemm<<<8192, 256, 0, stream>>>(w2, wconv, 512, 512, 8, 8);

    if (NBC == 64) {
        conv1_mfma<<<dim3(64, 4, 64), 256, 0, stream>>>(x, w1p, ss1, y1c, 0);
        conv_mfma6<8, 5, 656, false, true><<<dim3(7, 4, 64), 256, 0, stream>>>(
            y1c, wconv, y2, 4096, 819, 2, nullptr, sums + 1024);
        pack_all<<<14592, 256, 0, stream>>>(w3, w4, w5, wih, whh, wpk3, wpk4, wpk5, wihp, wfrag);
        bn_fin<<<2, 256, 0, stream>>>(sums + 1024, gamma, beta, 1, 1.0f / (64.0f * 819.0f), ss2);

        conv_mfma8<4, 2, 144, true, true><<<dim3(7, 2, 64), 256, 0, stream>>>(
            y2, wpk3, y3, 819, 409, 1, ss2, sums + 2048);
        bn_fin<<<2, 256, 0, stream>>>(sums + 2048, gamma, beta, 2, 1.0f / (64.0f * 409.0f), ss3);

        conv_mfma8<4, 1, 80, true, true><<<dim3(7, 2, 64), 256, 0, stream>>>(
            y3, wpk4, y4, 409, 409, 1, ss3, sums + 3072);
        bn_fin<<<2, 256, 0, stream>>>(sums + 3072, gamma, beta, 3, 1.0f / (64.0f * 409.0f), ss4);

        conv_mfma8<4, 1, 80, true, true><<<dim3(7, 2, 64), 256, 0, stream>>>(
            y4, wpk5, y5, 409, 409, 1, ss4, sums + 4096);
        bn_fin<<<2, 256, 0, stream>>>(sums + 4096, gamma, beta, 4, 1.0f / (64.0f * 409.0f), ss5);
    } else {
        for (int nb = 0; nb < 64; nb += NBC) {
            conv1_mfma<<<dim3(64, 4, NBC), 256, 0, stream>>>(x, w1p, ss1, y1c, nb);
            conv_mfma6<8, 5, 656, false, false><<<dim3(7, 4, NBC), 256, 0, stream>>>(
                y1c, wconv, y2 + (size_t)nb * 512 * 819, 4096, 819, 2, nullptr, nullptr);
        }
        bn_stats_v<<<dim3(512, 64), 256, 0, stream>>>(y2, sums + 1024, 819);
        bn_apply_v<<<dim3(512, 64), 256, 0, stream>>>(y2, sums + 1024, gamma, beta, 1, 819);

        pack_gemm<<<4096, 256, 0, stream>>>(w3, wconv, 512, 512, 4, 4);
        conv_mfma8<4, 2, 144, false, false><<<dim3(7, 2, 64), 256, 0, stream>>>(
            y2, wconv, y3, 819, 409, 1, nullptr, nullptr);
        bn_stats_v<<<dim3(512, 64), 256, 0, stream>>>(y3, sums + 2048, 409);
        bn_apply_v<<<dim3(512, 64), 256, 0, stream>>>(y3, sums + 2048, gamma, beta, 2, 409);

        pack_gemm<<<4096, 256, 0, stream>>>(w4, wconv, 512, 512, 3, 4);
        conv_mfma8<4, 1, 80, false, false><<<dim3(7, 2, 64), 256, 0, stream>>>(
            y3, wconv, y4, 409, 409, 1, nullptr, nullptr);
        bn_stats_v<<<dim3(512, 64), 256, 0, stream>>>(y4, sums + 3072, 409);
        bn_apply_v<<<dim3(512, 64), 256, 0, stream>>>(y4, sums + 3072, gamma, beta, 3, 409);

        pack_gemm<<<4096, 256, 0, stream>>>(w5, wconv, 512, 512, 3, 4);
        conv_mfma8<4, 1, 80, false, false><<<dim3(7, 2, 64), 256, 0, stream>>>(
            y4, wconv, y5, 409, 409, 1, nullptr, nullptr);
        bn_stats_v<<<dim3(512, 64), 256, 0, stream>>>(y5, sums + 4096, 409);
        bn_fin<<<2, 256, 0, stream>>>(sums + 4096, gamma, beta, 4, 1.0f / (64.0f * 409.0f), ss5);

        pack_gemm<<<1536, 256, 0, stream>>>(wih, wihp, 768, 512, 1, 1);
        pack_gruw<<<768, 256, 0, stream>>>(whh, wfrag);
    }

    // --- GRU (y5 BN folded into xproj staging via ss5) ---
    xproj_mfma<<<dim3(4, 6, 64), 256, 0, stream>>>(y5, wihp, bih, ss5, xp, tsamp);
    gru_mfma<<<64, 512, 0, stream>>>(xp, wfrag, hidden, bhh, hlast, tsamp);

    // --- contrastive head (y5 BN folded into total staging) ---
    pred_kernel<<<dim3(64, 12), 256, 0, stream>>>(hlast, wkw, wkb, pred);
    total_kernel<<<dim3(64, 12), 64, 0, stream>>>(y5, pred, ss5, totl, tsamp);
    final_kernel<<<1, 256, 0, stream>>>(totl, hlast, (float*)d_out);
}

// Round 12
// 2085.841 us; speedup vs baseline: 1.2457x; 1.2457x over previous
//
#include <hip/hip_runtime.h>
#include <hip/hip_bf16.h>

typedef __hip_bfloat16 bf16;
typedef short short8v __attribute__((ext_vector_type(8)));
typedef float float4v __attribute__((ext_vector_type(4)));

__device__ __forceinline__ float ld_f(const float* p, size_t i) { return p[i]; }
__device__ __forceinline__ float ld_f(const bf16* p, size_t i) { return __bfloat162float(p[i]); }
__device__ __forceinline__ float bfb_to_f(short u) {
    return __uint_as_float(((unsigned int)(unsigned short)u) << 16);
}
__device__ __forceinline__ short f_to_bf16bits(float v) {
    bf16 h = __float2bfloat16(v);
    short s; __builtin_memcpy(&s, &h, 2); return s;
}
__device__ __forceinline__ unsigned int bn_pair(unsigned int u, float sc, float sh) {
    float x0 = bfb_to_f((short)(u & 0xffffu));
    float x1 = bfb_to_f((short)(u >> 16));
    float y0 = fmaxf(fmaf(sc, x0, sh), 0.0f);
    float y1 = fmaxf(fmaf(sc, x1, sh), 0.0f);
    return (unsigned int)(unsigned short)f_to_bf16bits(y0) |
           ((unsigned int)(unsigned short)f_to_bf16bits(y1) << 16);
}
__device__ __forceinline__ float sigmoidf_(float x) { return 1.0f / (1.0f + expf(-x)); }

// ---------------------------------------------------------------------------
__global__ __launch_bounds__(256) void zero_kernel(float* __restrict__ p, int n) {
    int i = blockIdx.x * 256 + threadIdx.x;
    if (i < n) p[i] = 0.0f;
}

// ---------------------------------------------------------------------------
__global__ __launch_bounds__(256) void pack_gemm(const float* __restrict__ w, short* __restrict__ out,
                                                 int M, int CIN, int KW, int KWP) {
    int idx = blockIdx.x * 256 + threadIdx.x;
    int tot = M * CIN * KWP;
    if (idx >= tot) return;
    int co = idx / (CIN * KWP);
    int r = idx - co * (CIN * KWP);
    int ci = r / KWP, t = r - ci * KWP;
    float v = (t < KW) ? w[((size_t)co * CIN + ci) * KW + t] : 0.0f;
    out[idx] = f_to_bf16bits(v);
}

// ---------------------------------------------------------------------------
__global__ __launch_bounds__(256) void pack_gruw(const float* __restrict__ whh, short* __restrict__ wfrag) {
    int idx = blockIdx.x * 256 + threadIdx.x;
    if (idx >= 196608) return;
    int j = idx & 7;
    int lane = (idx >> 3) & 63;
    int f = idx >> 9;
    int wv = f / 48;
    int r = f - wv * 48;
    int mt = r >> 3, kc = r & 7;
    int m = lane & 15, quad = lane >> 4;
    int row = (wv * 6 + mt) * 16 + m;
    int col = kc * 32 + quad * 8 + j;
    wfrag[idx] = f_to_bf16bits(whh[(size_t)row * 256 + col]);
}

// ---------------------------------------------------------------------------
// consolidated pack: w3,w4,w5 (KWP=4), wih, whh-frag in ONE dispatch.
// ---------------------------------------------------------------------------
__global__ __launch_bounds__(256) void pack_all(const float* __restrict__ w3, const float* __restrict__ w4,
                                                const float* __restrict__ w5, const float* __restrict__ wih,
                                                const float* __restrict__ whh,
                                                short* __restrict__ o3, short* __restrict__ o4,
                                                short* __restrict__ o5, short* __restrict__ owih,
                                                short* __restrict__ ogru) {
    int idx = blockIdx.x * 256 + threadIdx.x;
    const int NC = 512 * 512 * 4;
    if (idx < NC) {
        int co = idx >> 11, r = idx & 2047;
        int ci = r >> 2, t = r & 3;
        o3[idx] = f_to_bf16bits(w3[((size_t)co * 512 + ci) * 4 + t]);
        return;
    }
    idx -= NC;
    if (idx < NC) {
        int co = idx >> 11, r = idx & 2047;
        int ci = r >> 2, t = r & 3;
        o4[idx] = (t < 3) ? f_to_bf16bits(w4[((size_t)co * 512 + ci) * 3 + t]) : 0;
        return;
    }
    idx -= NC;
    if (idx < NC) {
        int co = idx >> 11, r = idx & 2047;
        int ci = r >> 2, t = r & 3;
        o5[idx] = (t < 3) ? f_to_bf16bits(w5[((size_t)co * 512 + ci) * 3 + t]) : 0;
        return;
    }
    idx -= NC;
    if (idx < 393216) {
        owih[idx] = f_to_bf16bits(wih[idx]);
        return;
    }
    idx -= 393216;
    if (idx < 196608) {
        int j = idx & 7;
        int lane = (idx >> 3) & 63;
        int f = idx >> 9;
        int wv = f / 48;
        int r = f - wv * 48;
        int mt = r >> 3, kc = r & 7;
        int m = lane & 15, quad = lane >> 4;
        int row = (wv * 6 + mt) * 16 + m;
        int col = kc * 32 + quad * 8 + j;
        ogru[idx] = f_to_bf16bits(whh[(size_t)row * 256 + col]);
    }
}

// ---------------------------------------------------------------------------
__global__ __launch_bounds__(256) void bn_fin(const float* __restrict__ sums, const float* __restrict__ gamma,
                                              const float* __restrict__ beta, int layer, float invM,
                                              float* __restrict__ ss) {
    int c = blockIdx.x * 256 + threadIdx.x;
    if (c >= 512) return;
    float mean = sums[c] * invM;
    float var = sums[512 + c] * invM - mean * mean;
    float sc = rsqrtf(var + 1e-5f) * gamma[layer * 512 + c];
    ss[c] = sc;
    ss[512 + c] = beta[layer * 512 + c] - mean * sc;
}

// ---------------------------------------------------------------------------
// conv v6s: 128co x 128l tile, 1x4 waves, dbuf LDS, vectorized staging,
// fused input-BN / output-stats. 1-D grid with XCD-aware swizzle: the 4
// co-tiles sharing one input slab get linear ids {b, b+8, b+16, b+24} ->
// same XCD (%8 heuristic) -> staging reads hit that XCD's L2.
// Grid size must be NL*4*NB. Decode: co_t=(lin>>3)&3; u=((lin>>5)<<3)|(lin&7);
// l_t=u%NL; n=u/NL.
// ---------------------------------------------------------------------------
template <int KWP, int ST, int SPANP, bool BNIN, bool STATS>
__global__ __launch_bounds__(256, 3) void conv_mfma6(const bf16* __restrict__ in,
                                                     const short* __restrict__ wpk,
                                                     bf16* __restrict__ out,
                                                     int Lin, int Lout, int pad, int NL,
                                                     const float* __restrict__ ssin,
                                                     float* __restrict__ sums_out) {
    constexpr int KTOT = 512 * KWP;
    constexpr int NCHUNK = KTOT / 32;
    constexpr int CCC = 32 / KWP;
    constexpr int W16 = SPANP / 8;
    constexpr int NU = CCC * W16;
    constexpr int NLD = (NU + 255) / 256;

    const int lin = blockIdx.x;
    const int co_t = (lin >> 3) & 3;
    const int u = ((lin >> 5) << 3) | (lin & 7);
    const int l_t = u % NL;
    const int n = u / NL;
    const int l0 = l_t * 128;
    const int co0 = co_t * 128;

    const int tid = threadIdx.x;
    const int lane = tid & 63;
    const int wv = tid >> 6;
    const int m = lane & 15;
    const int quad = lane >> 4;
    const int nh = wv * 32;

    in += (size_t)n * 512 * Lin;
    out += (size_t)n * 512 * Lout;
    const short* ins = (const short*)in;

    __shared__ __align__(16) short As[2][128][40];
    __shared__ __align__(16) short rows[2][CCC][SPANP];
    __shared__ float bsum[STATS ? 128 : 1][2];

    const int base = ST * l0 - pad;
    const int g0a = base & ~7;
    const int off = base - g0a;

    const int arow = tid >> 2, aseg = tid & 3;

    float4v acc[8][2];
#pragma unroll
    for (int i = 0; i < 8; ++i) { acc[i][0] = (float4v){0,0,0,0}; acc[i][1] = (float4v){0,0,0,0}; }

    uint4 pa0, pa1;
    uint4 rbuf[NLD];

    auto load_stage = [&](int kc) {
        const int k0 = kc * 32;
        const int ci0 = kc * CCC;
        pa0 = *(const uint4*)(wpk + (size_t)(co0 + arow) * KTOT + k0 + aseg * 8);
        pa1 = *(const uint4*)(wpk + (size_t)(co0 + arow + 64) * KTOT + k0 + aseg * 8);
#pragma unroll
        for (int r = 0; r < NLD; ++r) {
            int e = tid + r * 256;
            if (NU % 256 == 0 || e < NU) {
                int cc = e / W16, col = e - cc * W16;
                int gs = g0a + col * 8;
                const short* src = ins + (size_t)(ci0 + cc) * Lin;
                if (gs >= 0 && gs + 8 <= Lin) {
                    rbuf[r] = *(const uint4*)(src + gs);
                } else {
                    float sc = 0.f, sh = 0.f;
                    if constexpr (BNIN) { sc = ssin[ci0 + cc]; sh = ssin[512 + ci0 + cc]; }
                    unsigned short tmp[8];
#pragma unroll
                    for (int j = 0; j < 8; ++j) {
                        int g = gs + j;
                        float xv = 0.f;
                        if (g >= 0 && g < Lin) {
                            xv = bfb_to_f(src[g]);
                            if constexpr (BNIN) xv = fmaxf(fmaf(sc, xv, sh), 0.0f);
                        }
                        tmp[j] = (unsigned short)f_to_bf16bits(xv);
                    }
                    uint4 v;
                    v.x = tmp[0] | ((unsigned int)tmp[1] << 16);
                    v.y = tmp[2] | ((unsigned int)tmp[3] << 16);
                    v.z = tmp[4] | ((unsigned int)tmp[5] << 16);
                    v.w = tmp[6] | ((unsigned int)tmp[7] << 16);
                    rbuf[r] = v;
                }
            }
        }
    };
    auto commit = [&](int buf, int kc) {
        *(uint4*)&As[buf][arow][aseg * 8] = pa0;
        *(uint4*)&As[buf][arow + 64][aseg * 8] = pa1;
        const int ci0 = kc * CCC;
#pragma unroll
        for (int r = 0; r < NLD; ++r) {
            int e = tid + r * 256;
            if (NU % 256 == 0 || e < NU) {
                int cc = e / W16, col = e - cc * W16;
                uint4 v = rbuf[r];
                if constexpr (BNIN) {
                    int gs = g0a + col * 8;
                    if (gs >= 0 && gs + 8 <= Lin) {
                        float sc = ssin[ci0 + cc], sh = ssin[512 + ci0 + cc];
                        v.x = bn_pair(v.x, sc, sh);
                        v.y = bn_pair(v.y, sc, sh);
                        v.z = bn_pair(v.z, sc, sh);
                        v.w = bn_pair(v.w, sc, sh);
                    }
                }
                *(uint4*)&rows[buf][cc][col * 8] = v;
            }
        }
    };

    if (STATS && tid < 128) { bsum[tid][0] = 0.f; bsum[tid][1] = 0.f; }
    load_stage(0);
    commit(0, 0);
    __syncthreads();

    for (int kc = 0; kc < NCHUNK; ++kc) {
        const int cur = kc & 1;
        if (kc + 1 < NCHUNK) load_stage(kc + 1);

        short8v afrag[8], bfrag[2];
#pragma unroll
        for (int s = 0; s < 8; ++s)
            afrag[s] = *(const short8v*)&As[cur][s * 16 + m][quad * 8];
#pragma unroll
        for (int t = 0; t < 2; ++t) {
            const int ll = nh + t * 16 + m;
            short8v bf;
            if constexpr (KWP == 8) {
                const short* rp = &rows[cur][quad][off + ST * ll];
#pragma unroll
                for (int j = 0; j < 8; ++j) bf[j] = rp[j];
            } else {
                const short* ra = &rows[cur][quad * 2 + 0][off + ST * ll];
                const short* rb = &rows[cur][quad * 2 + 1][off + ST * ll];
#pragma unroll
                for (int j = 0; j < 4; ++j) { bf[j] = ra[j]; bf[4 + j] = rb[j]; }
            }
            bfrag[t] = bf;
        }
#pragma unroll
        for (int s = 0; s < 8; ++s)
#pragma unroll
            for (int t = 0; t < 2; ++t)
                acc[s][t] = __builtin_amdgcn_mfma_f32_16x16x32_bf16(afrag[s], bfrag[t], acc[s][t], 0, 0, 0);

        if (kc + 1 < NCHUNK) commit(cur ^ 1, kc + 1);
        __syncthreads();
    }

    const bool v0 = (l0 + nh + m) < Lout;
    const bool v1 = (l0 + nh + 16 + m) < Lout;
#pragma unroll
    for (int t = 0; t < 2; ++t) {
        const int l = l0 + nh + t * 16 + m;
        if (t ? v1 : v0) {
#pragma unroll
            for (int s = 0; s < 8; ++s) {
#pragma unroll
                for (int reg = 0; reg < 4; ++reg) {
                    const int co = co0 + s * 16 + quad * 4 + reg;
                    out[(size_t)co * Lout + l] = __float2bfloat16(acc[s][t][reg]);
                }
            }
        }
    }

    if constexpr (STATS) {
#pragma unroll
        for (int s = 0; s < 8; ++s) {
            float p1[4], p2[4];
#pragma unroll
            for (int reg = 0; reg < 4; ++reg) {
                float a0 = v0 ? acc[s][0][reg] : 0.f;
                float a1 = v1 ? acc[s][1][reg] : 0.f;
                p1[reg] = a0 + a1;
                p2[reg] = a0 * a0 + a1 * a1;
            }
#pragma unroll
            for (int o = 1; o <= 8; o <<= 1) {
#pragma unroll
                for (int reg = 0; reg < 4; ++reg) {
                    p1[reg] += __shfl_xor(p1[reg], o);
                    p2[reg] += __shfl_xor(p2[reg], o);
                }
            }
            if (m == 0) {
#pragma unroll
                for (int reg = 0; reg < 4; ++reg) {
                    atomicAdd(&bsum[s * 16 + quad * 4 + reg][0], p1[reg]);
                    atomicAdd(&bsum[s * 16 + quad * 4 + reg][1], p2[reg]);
                }
            }
        }
        __syncthreads();
        if (tid < 128) {
            atomicAdd(&sums_out[co0 + tid], bsum[tid][0]);
            atomicAdd(&sums_out[512 + co0 + tid], bsum[tid][1]);
        }
    }
}

// ---------------------------------------------------------------------------
__global__ __launch_bounds__(256) void conv1_mfma(const float* __restrict__ x,
                                                  const short* __restrict__ w1p,
                                                  const float* __restrict__ ss,
                                                  bf16* __restrict__ y1c, int nbase) {
    const int l0 = blockIdx.x * 64;
    const int co0 = blockIdx.y * 128;
    const int nloc = blockIdx.z;
    const int n = nbase + nloc;
    const int tid = threadIdx.x;
    const int lane = tid & 63;
    const int wv = tid >> 6;
    const int m = lane & 15;
    const int quad = lane >> 4;

    __shared__ __align__(16) short xs[352];
    const int base = 5 * l0 - 3;
    for (int e = tid; e < 347; e += 256) {
        int g = base + e;
        float v = (g >= 0 && g < 20480) ? x[(size_t)n * 20480 + g] : 0.0f;
        xs[e] = f_to_bf16bits(v);
    }
    __syncthreads();

    const int lloc = wv * 16 + m;
    short8v bfrag;
    {
        const short* rp = &xs[5 * lloc + quad * 8];
#pragma unroll
        for (int j = 0; j < 8; ++j) bfrag[j] = rp[j];
    }
    float4v acc[8];
#pragma unroll
    for (int s = 0; s < 8; ++s) {
        short8v afrag = *(const short8v*)(w1p + (size_t)(co0 + s * 16 + m) * 32 + quad * 8);
        float4v z = (float4v){0.f, 0.f, 0.f, 0.f};
        acc[s] = __builtin_amdgcn_mfma_f32_16x16x32_bf16(afrag, bfrag, z, 0, 0, 0);
    }
    const int l = l0 + lloc;
#pragma unroll
    for (int s = 0; s < 8; ++s) {
#pragma unroll
        for (int reg = 0; reg < 4; ++reg) {
            const int co = co0 + s * 16 + quad * 4 + reg;
            float v = fmaxf(acc[s][reg] * ss[co] + ss[512 + co], 0.0f);
            y1c[((size_t)nloc * 512 + co) * 4096 + l] = __float2bfloat16(v);
        }
    }
}

// ---------------------------------------------------------------------------
__global__ __launch_bounds__(256) void conv1_stats(const float* __restrict__ x,
                                                   const float* __restrict__ w1,
                                                   float* __restrict__ sums) {
    const int n = blockIdx.x;
    const int tid = threadIdx.x;
    __shared__ __align__(16) float ws[5120];
    __shared__ __align__(16) float xs[5 * 256 + 10];
    for (int e = tid; e < 5120; e += 256) ws[e] = w1[e];
    const int co0 = tid, co1 = tid + 256;
    float a1_0 = 0.0f, a2_0 = 0.0f, a1_1 = 0.0f, a2_1 = 0.0f;
    for (int i = 0; i < 4; ++i) {
        const int c = blockIdx.y * 4 + i;
        const int base = c * 1280 - 3;
        __syncthreads();
        for (int e = tid; e < 1290; e += 256) {
            int g = base + e;
            xs[e] = (g >= 0 && g < 20480) ? x[(size_t)n * 20480 + g] : 0.0f;
        }
        __syncthreads();
        for (int l = 0; l < 256; ++l) {
            float y0 = 0.0f, y1v = 0.0f;
#pragma unroll
            for (int t = 0; t < 10; ++t) {
                float xv = xs[5 * l + t];
                y0 += ws[co0 * 10 + t] * xv;
                y1v += ws[co1 * 10 + t] * xv;
            }
            a1_0 += y0; a2_0 += y0 * y0;
            a1_1 += y1v; a2_1 += y1v * y1v;
        }
    }
    atomicAdd(&sums[co0], a1_0); atomicAdd(&sums[512 + co0], a2_0);
    atomicAdd(&sums[co1], a1_1); atomicAdd(&sums[512 + co1], a2_1);
}

// ---------------------------------------------------------------------------
__global__ __launch_bounds__(256) void bn_stats_v(const bf16* __restrict__ y, float* __restrict__ sums, int L) {
    const int c = blockIdx.x, n = blockIdx.y;
    const short* p = (const short*)y + ((size_t)n * 512 + c) * L;
    float s1 = 0.f, s2 = 0.f;
    for (int l = threadIdx.x; l < L; l += 256) {
        float v = bfb_to_f(p[l]);
        s1 += v; s2 += v * v;
    }
#pragma unroll
    for (int off = 32; off > 0; off >>= 1) {
        s1 += __shfl_down(s1, off, 64);
        s2 += __shfl_down(s2, off, 64);
    }
    __shared__ float r1[4], r2[4];
    const int lane = threadIdx.x & 63, wv = threadIdx.x >> 6;
    if (lane == 0) { r1[wv] = s1; r2[wv] = s2; }
    __syncthreads();
    if (threadIdx.x == 0) {
        atomicAdd(&sums[c], r1[0] + r1[1] + r1[2] + r1[3]);
        atomicAdd(&sums[512 + c], r2[0] + r2[1] + r2[2] + r2[3]);
    }
}

// ---------------------------------------------------------------------------
__global__ __launch_bounds__(256) void bn_apply_v(bf16* __restrict__ y, const float* __restrict__ sums,
                                                  const float* __restrict__ gamma, const float* __restrict__ beta,
                                                  int layer, int L) {
    const int c = blockIdx.x, n = blockIdx.y;
    const float invM = 1.0f / (64.0f * (float)L);
    float mean = sums[c] * invM;
    float var = sums[512 + c] * invM - mean * mean;
    float sc = rsqrtf(var + 1e-5f) * gamma[layer * 512 + c];
    float sh = beta[layer * 512 + c] - mean * sc;
    short* p = (short*)y + ((size_t)n * 512 + c) * L;
    for (int l = threadIdx.x; l < L; l += 256) {
        float v = bfb_to_f(p[l]);
        p[l] = f_to_bf16bits(fmaxf(v * sc + sh, 0.0f));
    }
}

// ---------------------------------------------------------------------------
// xproj with y5-BN folded into staging.
// ---------------------------------------------------------------------------
__global__ __launch_bounds__(256) void xproj_mfma(const bf16* __restrict__ y5,
                                                  const short* __restrict__ wihp,
                                                  const float* __restrict__ bih,
                                                  const float* __restrict__ ssy,
                                                  float* __restrict__ xp,
                                                  const int* __restrict__ tsamp) {
    const int t0 = blockIdx.x * 64;
    const int g0 = blockIdx.y * 128;
    const int b = blockIdx.z;
    const int tid = threadIdx.x;
    const int lane = tid & 63;
    const int wv = tid >> 6;
    const int m = lane & 15;
    const int quad = lane >> 4;
    const int ts = tsamp[0];

    __shared__ __align__(16) short As[128][40];
    __shared__ __align__(16) short Bt[32][66];

    float4v acc[8];
#pragma unroll
    for (int i = 0; i < 8; ++i) acc[i] = (float4v){0.f, 0.f, 0.f, 0.f};

    const short* y5s = (const short*)y5;
    for (int kc = 0; kc < 16; ++kc) {
        const int k0 = kc * 32;
        __syncthreads();
#pragma unroll
        for (int r = 0; r < 2; ++r) {
            int e = tid + r * 256;
            int row = e >> 2, seg = e & 3;
            *(uint4*)&As[row][seg * 8] =
                *(const uint4*)(wihp + (size_t)(g0 + row) * 512 + k0 + seg * 8);
        }
        for (int e = tid; e < 2048; e += 256) {
            int cc = e >> 6, tl = e & 63;
            float sc = ssy[k0 + cc], sh = ssy[512 + k0 + cc];
            float xv = bfb_to_f(y5s[((size_t)b * 512 + k0 + cc) * 409 + t0 + tl]);
            Bt[cc][tl] = f_to_bf16bits(fmaxf(fmaf(sc, xv, sh), 0.0f));
        }
        __syncthreads();
        short8v bfrag;
#pragma unroll
        for (int j = 0; j < 8; ++j) bfrag[j] = Bt[quad * 8 + j][wv * 16 + m];
#pragma unroll
        for (int s = 0; s < 8; ++s) {
            short8v afrag = *(const short8v*)&As[s * 16 + m][quad * 8];
            acc[s] = __builtin_amdgcn_mfma_f32_16x16x32_bf16(afrag, bfrag, acc[s], 0, 0, 0);
        }
    }
    const int t = t0 + wv * 16 + m;
    if (t <= ts) {
#pragma unroll
        for (int s = 0; s < 8; ++s) {
#pragma unroll
            for (int reg = 0; reg < 4; ++reg) {
                const int g = g0 + s * 16 + quad * 4 + reg;
                xp[((size_t)b * 256 + t) * 768 + g] = acc[s][reg] + bih[g];
            }
        }
    }
}

// ---------------------------------------------------------------------------
__global__ __launch_bounds__(512, 2) void gru_mfma(const float* __restrict__ xproj,
                                                   const short* __restrict__ wfrag,
                                                   const float* __restrict__ hidden,
                                                   const float* __restrict__ bhh,
                                                   float* __restrict__ hlast,
                                                   const int* __restrict__ tsamp) {
    const int b = blockIdx.x;
    const int tid = threadIdx.x;
    const int lane = tid & 63;
    const int wv = tid >> 6;
    const int m = lane & 15;
    const int quad = lane >> 4;

    __shared__ float hf[256];
    __shared__ __align__(16) short hbs[256];
    __shared__ float pre[768];

    short8v wreg[48];
    {
        const short* wb = wfrag + ((size_t)(wv * 48) * 64 + lane) * 8;
#pragma unroll
        for (int f = 0; f < 48; ++f) wreg[f] = *(const short8v*)(wb + (size_t)f * 512);
    }
    if (wv < 4) {
        float hv = hidden[(size_t)b * 256 + tid];
        hf[tid] = hv;
        hbs[tid] = f_to_bf16bits(hv);
    }
    const int ts = tsamp[0];
    const float* xb = xproj + (size_t)b * 256 * 768;
    float bhr = 0.f, bhz = 0.f, bhn = 0.f, nxr = 0.f, nxz = 0.f, nxn = 0.f;
    if (wv < 4) {
        bhr = bhh[tid]; bhz = bhh[256 + tid]; bhn = bhh[512 + tid];
        nxr = xb[tid]; nxz = xb[256 + tid]; nxn = xb[512 + tid];
    }

    for (int step = 0; step <= ts; ++step) {
        __syncthreads();
        float4v acc[6];
#pragma unroll
        for (int i = 0; i < 6; ++i) acc[i] = (float4v){0.f, 0.f, 0.f, 0.f};
#pragma unroll
        for (int kc = 0; kc < 8; ++kc) {
            short8v bfrag = *(const short8v*)&hbs[kc * 32 + quad * 8];
#pragma unroll
            for (int mt = 0; mt < 6; ++mt)
                acc[mt] = __builtin_amdgcn_mfma_f32_16x16x32_bf16(wreg[mt * 8 + kc], bfrag, acc[mt], 0, 0, 0);
        }
        if (m == 0) {
#pragma unroll
            for (int mt = 0; mt < 6; ++mt)
#pragma unroll
                for (int reg = 0; reg < 4; ++reg)
                    pre[wv * 96 + mt * 16 + quad * 4 + reg] = acc[mt][reg];
        }
        __syncthreads();
        if (wv < 4) {
            const int g = tid;
            float r = sigmoidf_(nxr + bhr + pre[g]);
            float z = sigmoidf_(nxz + bhz + pre[256 + g]);
            float nn = tanhf(nxn + r * (bhn + pre[512 + g]));
            float hnew = (1.0f - z) * nn + z * hf[g];
            hf[g] = hnew;
            hbs[g] = f_to_bf16bits(hnew);
            if (step < ts) {
                const float* xs = xb + (size_t)(step + 1) * 768;
                nxr = xs[g]; nxz = xs[256 + g]; nxn = xs[512 + g];
            }
        }
    }
    __syncthreads();
    if (wv < 4) hlast[(size_t)b * 256 + tid] = hf[tid];
}

// ---------------------------------------------------------------------------
__global__ __launch_bounds__(256) void pred_kernel(const float* __restrict__ hlast, const float* __restrict__ wkw,
                                                   const float* __restrict__ wkb, float* __restrict__ pred) {
    const int c = blockIdx.x, t = blockIdx.y;
    __shared__ __align__(16) float hs[256];
    hs[threadIdx.x] = hlast[(size_t)c * 256 + threadIdx.x];
    __syncthreads();
    for (int k = threadIdx.x; k < 512; k += 256) {
        const float* wr = wkw + ((size_t)t * 512 + k) * 256;
        float acc = 0.0f;
        for (int d = 0; d < 256; d += 4) {
            float4 w4 = *(const float4*)&wr[d];
            acc += w4.x * hs[d] + w4.y * hs[d + 1] + w4.z * hs[d + 2] + w4.w * hs[d + 3];
        }
        pred[((size_t)t * 64 + c) * 512 + k] = acc + wkb[(size_t)t * 512 + k];
    }
}

// ---------------------------------------------------------------------------
__global__ __launch_bounds__(64) void total_kernel(const bf16* __restrict__ y5, const float* __restrict__ pred,
                                                   const float* __restrict__ ssy,
                                                   float* __restrict__ total, const int* __restrict__ tsamp) {
    const int b = blockIdx.x, t = blockIdx.y;
    const int col = tsamp[0] + 1 + t;
    __shared__ __align__(16) float es[512];
    for (int k = threadIdx.x; k < 512; k += 64) {
        float xv = ld_f(y5, ((size_t)b * 512 + k) * 409 + col);
        es[k] = fmaxf(fmaf(ssy[k], xv, ssy[512 + k]), 0.0f);
    }
    __syncthreads();
    const int c = threadIdx.x;
    const float* pr = pred + ((size_t)t * 64 + c) * 512;
    float acc = 0.0f;
    for (int k = 0; k < 512; k += 4) {
        float4 p4 = *(const float4*)&pr[k];
        acc += p4.x * es[k] + p4.y * es[k + 1] + p4.z * es[k + 2] + p4.w * es[k + 3];
    }
    total[((size_t)t * 64 + b) * 64 + c] = acc;
}

// ---------------------------------------------------------------------------
__global__ __launch_bounds__(256) void final_kernel(const float* __restrict__ total, const float* __restrict__ hlast,
                                                    float* __restrict__ out) {
    __shared__ float rowM[768], rowS[768];
    __shared__ float red[256];
    __shared__ int cnt[64];
    const int tid = threadIdx.x;
    float local = 0.0f;
    for (int row = tid; row < 768; row += 256) {
        const float* r = total + (size_t)row * 64;
        float m = r[0];
        for (int c = 1; c < 64; ++c) m = fmaxf(m, r[c]);
        float s = 0.0f;
        for (int c = 0; c < 64; ++c) s += expf(r[c] - m);
        rowM[row] = m; rowS[row] = s;
        int bcol = row & 63;
        local += r[bcol] - m - logf(s);
    }
    red[tid] = local;
    __syncthreads();
    for (int o = 128; o > 0; o >>= 1) {
        if (tid < o) red[tid] += red[tid + o];
        __syncthreads();
    }
    if (tid == 0) out[1] = red[0] / (-768.0f);
    if (tid < 64) {
        const int c = tid;
        float best = -1e30f; int bi = -1;
        for (int b = 0; b < 64; ++b) {
            int row = 11 * 64 + b;
            float v = expf(total[(size_t)row * 64 + c] - rowM[row]) / rowS[row];
            if (v > best) { best = v; bi = b; }
        }
        cnt[c] = (bi == c) ? 1 : 0;
    }
    __syncthreads();
    if (tid == 0) {
        int s = 0;
        for (int c = 0; c < 64; ++c) s += cnt[c];
        out[0] = (float)s / 64.0f;
    }
    for (int i = tid; i < 16384; i += 256) out[2 + i] = hlast[i];
}

// ---------------------------------------------------------------------------
extern "C" void kernel_launch(void* const* d_in, const int* in_sizes, int n_in,
                              void* d_out, int out_size, void* d_ws, size_t ws_size,
                              hipStream_t stream) {
    const float *x = nullptr, *hidden = nullptr, *gamma = nullptr, *beta = nullptr;
    const float *wih = nullptr, *whh = nullptr, *bih = nullptr, *bhh = nullptr;
    const float *wkw = nullptr, *wkb = nullptr;
    const float *w1 = nullptr, *w2 = nullptr, *w3 = nullptr, *w4 = nullptr, *w5 = nullptr;
    const int* tsamp = nullptr;
    for (int i = 0; i < n_in; ++i) {
        const float* p = (const float*)d_in[i];
        switch (in_sizes[i]) {
            case 1310720: x = p; break;
            case 16384:   hidden = p; break;
            case 2560:    if (!gamma) gamma = p; else beta = p; break;
            case 393216:  wih = p; break;
            case 196608:  whh = p; break;
            case 768:     if (!bih) bih = p; else bhh = p; break;
            case 1572864: wkw = p; break;
            case 6144:    wkb = p; break;
            case 1:       tsamp = (const int*)d_in[i]; break;
            case 5120:    w1 = p; break;
            case 2097152: w2 = p; break;
            case 1048576: w3 = p; break;
            case 786432:  if (!w4) w4 = p; else w5 = p; break;
            default: break;
        }
    }

    char* ws = (char*)d_ws;
    const size_t SLOT_B = 57872384ull;
    int NBC = 8;
    if (ws_size >= SLOT_B + 64ull * 4194304ull + 98304ull) NBC = 64;
    else if (ws_size >= SLOT_B + 32ull * 4194304ull + 98304ull) NBC = 32;
    else if (ws_size >= SLOT_B + 16ull * 4194304ull + 98304ull) NBC = 16;

    bf16*  y2    = (bf16*)(ws + 0);
    bf16*  y4    = (bf16*)(ws + 0);
    float* xp    = (float*)(ws + 0);
    short* wconv = (short*)(ws + 53676032ull);
    bf16*  y1c   = (bf16*)(ws + SLOT_B);
    bf16*  y3    = (bf16*)(ws + SLOT_B);
    bf16*  y5    = (bf16*)(ws + SLOT_B);
    const size_t tail = SLOT_B + (size_t)NBC * 4194304ull;
    float* sums  = (float*)(ws + tail);
    float* ss1   = (float*)(ws + tail + 20480ull);
    float* ss2   = (float*)(ws + tail + 24576ull);
    float* ss3   = (float*)(ws + tail + 28672ull);
    float* ss4   = (float*)(ws + tail + 32768ull);
    float* ss5   = (float*)(ws + tail + 36864ull);
    short* w1p   = (short*)(ws + tail + 40960ull);

    float* hlast = (float*)(ws + 54855680ull);
    float* pred  = (float*)(ws + 54921216ull);
    float* totl  = (float*)(ws + 56494080ull);

    short *wpk3, *wpk4, *wpk5, *wihp, *wfrag;
    if (NBC == 64) {
        wpk3  = (short*)(ws + SLOT_B + 33554432ull);
        wpk4  = wpk3 + 1048576;
        wpk5  = wpk4 + 1048576;
        wihp  = wpk5 + 1048576;
        wfrag = wihp + 393216;
    } else {
        wpk3 = wpk4 = wpk5 = wconv;
        wihp  = (short*)(ws + 53676032ull);
        wfrag = (short*)(ws + 54462464ull);
    }

    // --- layer-1 stats + packs ---
    zero_kernel<<<20, 256, 0, stream>>>(sums, 5120);
    conv1_stats<<<dim3(64, 4), 256, 0, stream>>>(x, w1, sums);
    bn_fin<<<2, 256, 0, stream>>>(sums, gamma, beta, 0, 1.0f / (64.0f * 4096.0f), ss1);
    pack_gemm<<<64, 256, 0, stream>>>(w1, w1p, 512, 1, 10, 32);
    pack_gemm<<<8192, 256, 0, stream>>>(w2, wconv, 512, 512, 8, 8);

    if (NBC == 64) {
        conv1_mfma<<<dim3(64, 4, 64), 256, 0, stream>>>(x, w1p, ss1, y1c, 0);
        conv_mfma6<8, 5, 656, false, true><<<7 * 4 * 64, 256, 0, stream>>>(
            y1c, wconv, y2, 4096, 819, 2, 7, nullptr, sums + 1024);
        pack_all<<<14592, 256, 0, stream>>>(w3, w4, w5, wih, whh, wpk3, wpk4, wpk5, wihp, wfrag);
        bn_fin<<<2, 256, 0, stream>>>(sums + 1024, gamma, beta, 1, 1.0f / (64.0f * 819.0f), ss2);

        conv_mfma6<4, 2, 272, true, true><<<4 * 4 * 64, 256, 0, stream>>>(
            y2, wpk3, y3, 819, 409, 1, 4, ss2, sums + 2048);
        bn_fin<<<2, 256, 0, stream>>>(sums + 2048, gamma, beta, 2, 1.0f / (64.0f * 409.0f), ss3);

        conv_mfma6<4, 1, 144, true, true><<<4 * 4 * 64, 256, 0, stream>>>(
            y3, wpk4, y4, 409, 409, 1, 4, ss3, sums + 3072);
        bn_fin<<<2, 256, 0, stream>>>(sums + 3072, gamma, beta, 3, 1.0f / (64.0f * 409.0f), ss4);

        conv_mfma6<4, 1, 144, true, true><<<4 * 4 * 64, 256, 0, stream>>>(
            y4, wpk5, y5, 409, 409, 1, 4, ss4, sums + 4096);
        bn_fin<<<2, 256, 0, stream>>>(sums + 4096, gamma, beta, 4, 1.0f / (64.0f * 409.0f), ss5);
    } else {
        for (int nb = 0; nb < 64; nb += NBC) {
            conv1_mfma<<<dim3(64, 4, NBC), 256, 0, stream>>>(x, w1p, ss1, y1c, nb);
            conv_mfma6<8, 5, 656, false, false><<<7 * 4 * NBC, 256, 0, stream>>>(
                y1c, wconv, y2 + (size_t)nb * 512 * 819, 4096, 819, 2, 7, nullptr, nullptr);
        }
        bn_stats_v<<<dim3(512, 64), 256, 0, stream>>>(y2, sums + 1024, 819);
        bn_apply_v<<<dim3(512, 64), 256, 0, stream>>>(y2, sums + 1024, gamma, beta, 1, 819);

        pack_gemm<<<4096, 256, 0, stream>>>(w3, wconv, 512, 512, 4, 4);
        conv_mfma6<4, 2, 272, false, false><<<4 * 4 * 64, 256, 0, stream>>>(
            y2, wconv, y3, 819, 409, 1, 4, nullptr, nullptr);
        bn_stats_v<<<dim3(512, 64), 256, 0, stream>>>(y3, sums + 2048, 409);
        bn_apply_v<<<dim3(512, 64), 256, 0, stream>>>(y3, sums + 2048, gamma, beta, 2, 409);

        pack_gemm<<<4096, 256, 0, stream>>>(w4, wconv, 512, 512, 3, 4);
        conv_mfma6<4, 1, 144, false, false><<<4 * 4 * 64, 256, 0, stream>>>(
            y3, wconv, y4, 409, 409, 1, 4, nullptr, nullptr);
        bn_stats_v<<<dim3(512, 64), 256, 0, stream>>>(y4, sums + 3072, 409);
        bn_apply_v<<<dim3(512, 64), 256, 0, stream>>>(y4, sums + 3072, gamma, beta, 3, 409);

        pack_gemm<<<4096, 256, 0, stream>>>(w5, wconv, 512, 512, 3, 4);
        conv_mfma6<4, 1, 144, false, false><<<4 * 4 * 64, 256, 0, stream>>>(
            y4, wconv, y5, 409, 409, 1, 4, nullptr, nullptr);
        bn_stats_v<<<dim3(512, 64), 256, 0, stream>>>(y5, sums + 4096, 409);
        bn_fin<<<2, 256, 0, stream>>>(sums + 4096, gamma, beta, 4, 1.0f / (64.0f * 409.0f), ss5);

        pack_gemm<<<1536, 256, 0, stream>>>(wih, wihp, 768, 512, 1, 1);
        pack_gruw<<<768, 256, 0, stream>>>(whh, wfrag);
    }

    // --- GRU (y5 BN folded into xproj staging via ss5) ---
    xproj_mfma<<<dim3(4, 6, 64), 256, 0, stream>>>(y5, wihp, bih, ss5, xp, tsamp);
    gru_mfma<<<64, 512, 0, stream>>>(xp, wfrag, hidden, bhh, hlast, tsamp);

    // --- contrastive head (y5 BN folded into total staging) ---
    pred_kernel<<<dim3(64, 12), 256, 0, stream>>>(hlast, wkw, wkb, pred);
    total_kernel<<<dim3(64, 12), 64, 0, stream>>>(y5, pred, ss5, totl, tsamp);
    final_kernel<<<1, 256, 0, stream>>>(totl, hlast, (float*)d_out);
}